// Round 23
// baseline (45.385 us; speedup 1.0000x reference)
//
#include <hip/hip_runtime.h>
#include <hip/hip_bf16.h>

typedef short bf16x8 __attribute__((ext_vector_type(8)));
typedef float f32x4 __attribute__((ext_vector_type(4)));
typedef float f32x16 __attribute__((ext_vector_type(16)));
typedef unsigned short u16;
typedef u16 u16x8 __attribute__((ext_vector_type(8)));
typedef unsigned int u32;
typedef u32 u32x4 __attribute__((ext_vector_type(4)));

constexpr int NB = 8, NT = 2048, NC = 1024, NH = 64;
constexpr float L2E = 1.4426950408889634f;
constexpr float MBIAS = -23.083120654223414f;   // -16*log2(e): fixed softmax max

__device__ __forceinline__ u16 f2bf(float f) {
  __hip_bfloat16 h = __float2bfloat16(f);
  return __builtin_bit_cast(u16, h);
}
__device__ __forceinline__ bf16x8 ldsv8(const u16* p) {
  return __builtin_bit_cast(bf16x8, *(const u16x8*)p);
}
__device__ __forceinline__ u32 pk2(float a, float b) {
  return (u32)f2bf(a) | ((u32)f2bf(b) << 16);
}
__device__ __forceinline__ void glds16(const void* g, void* l) {
  __builtin_amdgcn_global_load_lds((const __attribute__((address_space(1))) void*)g,
                                   (__attribute__((address_space(3))) void*)l, 16, 0, 0);
}

// ---------------- kernel 0: W fp32 [C][H] -> bf16 W^T [3][H][C]; Wq scaled 0.125
__global__ __launch_bounds__(256) void wconv(const float* __restrict__ wk,
                                             const float* __restrict__ wq,
                                             const float* __restrict__ wv,
                                             u16* __restrict__ wb) {
  int idx = blockIdx.x * 256 + threadIdx.x;   // 3*64*1024
  int m = idx >> 16, rem = idx & 65535;
  int n = rem >> 10, kk = rem & 1023;
  const float* s = (m == 0) ? wq : ((m == 1) ? wk : wv);
  float f = s[kk * NH + n];
  if (m == 0) f *= 0.125f;
  wb[idx] = f2bf(f);
}

// ---------------- kernel 1: fused QKV projection — 64-row tiles, 2-deep pipeline.
// 256 blocks x 512 thr; 8 waves = 4 row-groups(16) x 2 col-groups(96).
// Double-buffered x(16KB)+W(24KB) staging = 80KB LDS -> 2 blocks/CU (16 waves/CU,
// same occupancy as r16/r20) with HALF the W L2 traffic (W amortized over 64 rows).
// Ledger: 5 VMEM/stage; steady vmcnt(5), tail vmcnt(0).
__global__ __launch_bounds__(512, 4)
__attribute__((amdgpu_waves_per_eu(4, 4)))
void qkv_proj(const float* __restrict__ x,
              const u16* __restrict__ wb,
              u16* __restrict__ qg,
              u16* __restrict__ kg,
              u16* __restrict__ vtg) {
  __shared__ __align__(16) float xbuf[2][64 * 64];   // 16 KB each
  __shared__ __align__(16) u16 wlds[2][192 * 64];    // 24 KB each
  const int tid = threadIdx.x, w = tid >> 6, l = tid & 63;
  const int lr = l & 15, lg = l >> 4;
  const int rg = w & 3, cg = w >> 2;                 // row-group, col-group
  const int row0 = blockIdx.x * 64;

  f32x4 acc[6];
#pragma unroll
  for (int nt = 0; nt < 6; ++nt) acc[nt] = (f32x4){0.f, 0.f, 0.f, 0.f};

  // stage x (16KB: 2 glds/lane) + W (24KB: 3 glds/lane) for k-block kb.
  // content[row][c] = src[row][c ^ ((row&7)<<4)] for both (r21-proven geometry).
#define GSTAGE(buf, kb)                                                       \
  {                                                                           \
    _Pragma("unroll")                                                         \
    for (int i = 0; i < 2; ++i) {                                             \
      int row = w * 8 + i * 4 + (l >> 4);                                     \
      int srci = ((l & 15) * 16) ^ ((row & 7) << 4);                          \
      glds16((const char*)x + (size_t)(row0 + row) * 4096 + (kb) * 256 + srci,\
             (char*)&xbuf[buf][0] + w * 2048 + i * 1024);                     \
    }                                                                         \
    _Pragma("unroll")                                                         \
    for (int i = 0; i < 3; ++i) {                                             \
      int seg = w * 3 + i;                                                    \
      int wrow = seg * 8 + (l >> 3);                                          \
      int wsrc = ((l & 7) * 16) ^ ((wrow & 7) << 4);                          \
      glds16((const char*)wb + (size_t)wrow * 2048 + (kb) * 128 + wsrc,       \
             (char*)&wlds[buf][0] + seg * 1024);                              \
    }                                                                         \
  }

  GSTAGE(0, 0);
  GSTAGE(1, 1);

#pragma unroll
  for (int kb = 0; kb < 16; ++kb) {
    const int cur = kb & 1;
    // ---- gate 1: buffer(kb) complete; stage(kb+1) keeps flying ----
    if (kb < 15) {
      asm volatile("s_waitcnt vmcnt(5)" ::: "memory");
    } else {
      asm volatile("s_waitcnt vmcnt(0)" ::: "memory");
    }
    __builtin_amdgcn_sched_barrier(0);
    __builtin_amdgcn_s_barrier();
    // ---- hoisted frag reads ----
    f32x4 xv[2][2];
#pragma unroll
    for (int ks = 0; ks < 2; ++ks) {
      int rowl = rg * 16 + lr;
      int sz = (lr & 7) << 4;
      int c0 = ks * 128 + lg * 32;
      xv[ks][0] = *(const f32x4*)((const char*)&xbuf[cur][0] + rowl * 256 + (c0 ^ sz));
      xv[ks][1] = *(const f32x4*)((const char*)&xbuf[cur][0] + rowl * 256 + ((c0 + 16) ^ sz));
    }
    bf16x8 bfr[6][2];
#pragma unroll
    for (int nt = 0; nt < 6; ++nt)
#pragma unroll
      for (int ks = 0; ks < 2; ++ks) {
        int wrow = cg * 96 + nt * 16 + lr;
        int cb = (ks * 64 + lg * 16) ^ ((lr & 7) << 4);
        bfr[nt][ks] = ldsv8((const u16*)((const char*)&wlds[cur][0] + wrow * 128 + cb));
      }
    // ---- gate 2: all waves done reading buffer(kb) ----
    asm volatile("s_waitcnt lgkmcnt(0)" ::: "memory");
    __builtin_amdgcn_sched_barrier(0);
    __builtin_amdgcn_s_barrier();
    if (kb < 14) GSTAGE(cur, kb + 2);     // overwrite freed buffer(kb)
    // ---- convert + MFMA (overlaps prefetch flight) ----
    bf16x8 af[2];
#pragma unroll
    for (int ks = 0; ks < 2; ++ks) {
      u16x8 tt;
#pragma unroll
      for (int j = 0; j < 4; ++j) {
        tt[j]     = f2bf(xv[ks][0][j]);
        tt[j + 4] = f2bf(xv[ks][1][j]);
      }
      af[ks] = __builtin_bit_cast(bf16x8, tt);
    }
#pragma unroll
    for (int nt = 0; nt < 6; ++nt)
#pragma unroll
      for (int ks = 0; ks < 2; ++ks)
        acc[nt] = __builtin_amdgcn_mfma_f32_16x16x32_bf16(af[ks], bfr[nt][ks], acc[nt], 0, 0, 0);
  }
#undef GSTAGE

  // epilogue aliased into dead staging (xbuf: 32KB >= 27KB needed)
  u16* qs  = (u16*)&xbuf[0][0];          // [64][72]
  u16* ksl = qs + 64 * 72;               // [64][72]
  u16* vt  = ksl + 64 * 72;              // [64][72] (rows = h, cols = local t)
#pragma unroll
  for (int nt = 0; nt < 6; ++nt)
#pragma unroll
    for (int r = 0; r < 4; ++r) {
      int g = cg * 96 + nt * 16 + lr;
      int rl = rg * 16 + lg * 4 + r;
      u16 bv = f2bf(acc[nt][r]);
      if (g < 64)       qs[rl * 72 + g] = bv;
      else if (g < 128) ksl[rl * 72 + (g - 64)] = bv;
      else              vt[(g - 128) * 72 + rl] = bv;
    }
  __syncthreads();
  {
    int b = row0 >> 11, t0 = row0 & 2047;
    int row = tid >> 3, c8 = (tid & 7) * 8;   // 64 rows x 64 cols, vec8
    *(u16x8*)(qg + (size_t)(row0 + row) * NH + c8) = *(const u16x8*)&qs[row * 72 + c8];
    *(u16x8*)(kg + (size_t)(row0 + row) * NH + c8) = *(const u16x8*)&ksl[row * 72 + c8];
    *(u16x8*)(vtg + ((size_t)b * NH + row) * NT + t0 + c8) = *(const u16x8*)&vt[row * 72 + c8];
  }
}

// ---------------- kernel 2: causal flash — merged-pair blocks for full TLP (r20).
__global__ __launch_bounds__(512, 2)
__attribute__((amdgpu_waves_per_eu(2, 2)))
void flash(const u16* __restrict__ qg,
           const u16* __restrict__ kg,
           const u16* __restrict__ vtg,
           float* __restrict__ out) {
  __shared__ __align__(16) u16 stg[8][2][4096];     // 128 KB: [wave][K/V][64x64]
  float* om = (float*)&stg[0][0][0];                // [8][32][68] f32 aliased
  const int tid = threadIdx.x, w = tid >> 6, l = tid & 63;
  const int l31 = l & 31, hb = l >> 5;
  const int b = blockIdx.x & 7, gp = blockIdx.x >> 3;   // gp = 0..31
  const int tA = gp, tB = 63 - gp;
  const int nktA = (tA + 2) >> 1, nktB = (tB + 2) >> 1;
  const int ntot = nktA + nktB;

  bf16x8 qfA[4], qfB[4];
  {
    const u16* qpA = qg + ((size_t)b * NT + tA * 32 + l31) * NH;
    const u16* qpB = qg + ((size_t)b * NT + tB * 32 + l31) * NH;
#pragma unroll
    for (int ks = 0; ks < 4; ++ks) {
      qfA[ks] = ldsv8(qpA + ks * 16 + hb * 8);
      qfB[ks] = ldsv8(qpB + ks * 16 + hb * 8);
    }
  }
  f32x16 oA0, oA1, oB0, oB1;
#pragma unroll
  for (int r = 0; r < 16; ++r) { oA0[r] = 0.f; oA1[r] = 0.f; oB0[r] = 0.f; oB1[r] = 0.f; }
  float lsA = 0.f, lsB = 0.f;
  const char* kbase = (const char*)(kg + (size_t)b * NT * NH);
  const char* vbase = (const char*)(vtg + (size_t)b * NH * NT);
  char* kst = (char*)&stg[w][0][0];
  char* vst = (char*)&stg[w][1][0];

#define STAGE_K(kt_)                                                          \
  {                                                                           \
    const int kvb_ = (kt_) * 64;                                              \
    int r8 = l >> 3;                                                          \
    int src = ((l & 7) * 16) ^ (r8 << 4);                                     \
    _Pragma("unroll")                                                         \
    for (int j = 0; j < 8; ++j)                                               \
      glds16(kbase + (size_t)(kvb_ + j * 8 + r8) * 128 + src, kst + j * 1024);\
  }
#define STAGE_V(kt_)                                                          \
  {                                                                           \
    const int kvb_ = (kt_) * 64;                                              \
    int r8 = l >> 3;                                                          \
    int src = ((l & 7) * 16) ^ (r8 << 4);                                     \
    _Pragma("unroll")                                                         \
    for (int j = 0; j < 8; ++j)                                               \
      glds16(vbase + (size_t)(j * 8 + r8) * 4096 + kvb_ * 2 + src, vst + j * 1024);\
  }
#define KT_OF(c_) (((c_) < nktA) ? (c_) : ((c_) - nktA))

  { const int kt0 = KT_OF(w); STAGE_K(kt0); STAGE_V(kt0); }

#pragma unroll 1
  for (int c = w; c < ntot; c += 8) {
    const bool isA = (c < nktA);
    const int kt = isA ? c : (c - nktA);
    const int t_ = isA ? tA : tB;
    const int kvb = kt * 64;
    const bool pre = (c + 8 < ntot);
    const int ktn = pre ? KT_OF(c + 8) : 0;
    asm volatile("s_waitcnt vmcnt(8)" ::: "memory");
    __builtin_amdgcn_sched_barrier(0);
    const int key = (l31 & 7) << 4;
    bf16x8 kf[4][2];
#pragma unroll
    for (int ks = 0; ks < 4; ++ks)
#pragma unroll
      for (int half = 0; half < 2; ++half) {
        int row = half * 32 + l31;
        int col = ks * 32 + hb * 16;
        kf[ks][half] = ldsv8((const u16*)(kst + row * 128 + (col ^ key)));
      }
    asm volatile("s_waitcnt lgkmcnt(0)" ::: "memory");
    __builtin_amdgcn_sched_barrier(0);
    if (pre) STAGE_K(ktn);

    f32x16 s0, s1;
#pragma unroll
    for (int r = 0; r < 16; ++r) { s0[r] = 0.f; s1[r] = 0.f; }
    __builtin_amdgcn_s_setprio(1);
    if (isA) {
#pragma unroll
      for (int ks = 0; ks < 4; ++ks) {
        s0 = __builtin_amdgcn_mfma_f32_32x32x16_bf16(kf[ks][0], qfA[ks], s0, 0, 0, 0);
        s1 = __builtin_amdgcn_mfma_f32_32x32x16_bf16(kf[ks][1], qfA[ks], s1, 0, 0, 0);
      }
    } else {
#pragma unroll
      for (int ks = 0; ks < 4; ++ks) {
        s0 = __builtin_amdgcn_mfma_f32_32x32x16_bf16(kf[ks][0], qfB[ks], s0, 0, 0, 0);
        s1 = __builtin_amdgcn_mfma_f32_32x32x16_bf16(kf[ks][1], qfB[ks], s1, 0, 0, 0);
      }
    }
    __builtin_amdgcn_s_setprio(0);
    if (kvb + 63 > t_ * 32) {
      const int qrow_ = t_ * 32 + l31;
#pragma unroll
      for (int r = 0; r < 16; ++r) {
        int kv0 = kvb + (r & 3) + 8 * (r >> 2) + 4 * hb;
        if (kv0 > qrow_)      s0[r] = -1e30f;
        if (kv0 + 32 > qrow_) s1[r] = -1e30f;
      }
    }
    float p0[16], p1[16];
    float lst = 0.f;
#pragma unroll
    for (int r = 0; r < 16; ++r) {
      p0[r] = exp2f(fmaf(s0[r], L2E, MBIAS));
      p1[r] = exp2f(fmaf(s1[r], L2E, MBIAS));
      lst += p0[r] + p1[r];
    }
    if (isA) lsA += lst; else lsB += lst;
    u32 pf[2][2][4];
#pragma unroll
    for (int kvt = 0; kvt < 2; ++kvt) {
      const float* pp = kvt ? p1 : p0;
#pragma unroll
      for (int ks2 = 0; ks2 < 2; ++ks2) {
        u32 a0 = pk2(pp[8 * ks2 + 0], pp[8 * ks2 + 1]);
        u32 a1 = pk2(pp[8 * ks2 + 2], pp[8 * ks2 + 3]);
        u32 b0 = pk2(pp[8 * ks2 + 4], pp[8 * ks2 + 5]);
        u32 b1 = pk2(pp[8 * ks2 + 6], pp[8 * ks2 + 7]);
        u32 e0 = hb ? a0 : b0, e1 = hb ? a1 : b1;
        e0 = __shfl_xor(e0, 32);
        e1 = __shfl_xor(e1, 32);
        pf[kvt][ks2][0] = hb ? e0 : a0;
        pf[kvt][ks2][1] = hb ? e1 : a1;
        pf[kvt][ks2][2] = hb ? b0 : e0;
        pf[kvt][ks2][3] = hb ? b1 : e1;
      }
    }
    if (pre) {
      asm volatile("s_waitcnt vmcnt(8)" ::: "memory");
    } else {
      asm volatile("s_waitcnt vmcnt(0)" ::: "memory");
    }
    __builtin_amdgcn_sched_barrier(0);
    bf16x8 vf[2][2][2];
#pragma unroll
    for (int ht = 0; ht < 2; ++ht)
#pragma unroll
      for (int kvt = 0; kvt < 2; ++kvt)
#pragma unroll
        for (int ks2 = 0; ks2 < 2; ++ks2) {
          int row = ht * 32 + l31;
          int col = kvt * 64 + ks2 * 32 + hb * 16;
          vf[ht][kvt][ks2] = ldsv8((const u16*)(vst + row * 128 + (col ^ key)));
        }
    asm volatile("s_waitcnt lgkmcnt(0)" ::: "memory");
    __builtin_amdgcn_sched_barrier(0);
    if (pre) STAGE_V(ktn);

    __builtin_amdgcn_s_setprio(1);
    if (isA) {
#pragma unroll
      for (int ht = 0; ht < 2; ++ht)
#pragma unroll
        for (int kvt = 0; kvt < 2; ++kvt)
#pragma unroll
          for (int ks2 = 0; ks2 < 2; ++ks2) {
            u32x4 pw = {pf[kvt][ks2][0], pf[kvt][ks2][1], pf[kvt][ks2][2], pf[kvt][ks2][3]};
            bf16x8 pv = __builtin_bit_cast(bf16x8, pw);
            if (ht == 0) oA0 = __builtin_amdgcn_mfma_f32_32x32x16_bf16(vf[0][kvt][ks2], pv, oA0, 0, 0, 0);
            else         oA1 = __builtin_amdgcn_mfma_f32_32x32x16_bf16(vf[1][kvt][ks2], pv, oA1, 0, 0, 0);
          }
    } else {
#pragma unroll
      for (int ht = 0; ht < 2; ++ht)
#pragma unroll
        for (int kvt = 0; kvt < 2; ++kvt)
#pragma unroll
          for (int ks2 = 0; ks2 < 2; ++ks2) {
            u32x4 pw = {pf[kvt][ks2][0], pf[kvt][ks2][1], pf[kvt][ks2][2], pf[kvt][ks2][3]};
            bf16x8 pv = __builtin_bit_cast(bf16x8, pw);
            if (ht == 0) oB0 = __builtin_amdgcn_mfma_f32_32x32x16_bf16(vf[0][kvt][ks2], pv, oB0, 0, 0, 0);
            else         oB1 = __builtin_amdgcn_mfma_f32_32x32x16_bf16(vf[1][kvt][ks2], pv, oB1, 0, 0, 0);
          }
    }
    __builtin_amdgcn_s_setprio(0);
  }
#undef STAGE_K
#undef STAGE_V
#undef KT_OF
  lsA += __shfl_xor(lsA, 32);
  lsB += __shfl_xor(lsB, 32);

#pragma unroll 1
  for (int ph = 0; ph < 2; ++ph) {
    __syncthreads();
    {
      float* dst = &om[w * 2176 + l31 * 68];
#pragma unroll
      for (int ht = 0; ht < 2; ++ht)
#pragma unroll
        for (int rq = 0; rq < 4; ++rq) {
          f32x4 q4;
#pragma unroll
          for (int cc = 0; cc < 4; ++cc) {
            int idx = 4 * rq + cc;
            q4[cc] = ph ? (ht ? oB1[idx] : oB0[idx]) : (ht ? oA1[idx] : oA0[idx]);
          }
          *(f32x4*)&dst[ht * 32 + rq * 8 + hb * 4] = q4;
        }
      if (hb == 0) dst[64] = ph ? lsB : lsA;
    }
    __syncthreads();
    {
      const int t_ = ph ? tB : tA;
      int row = tid >> 4, c4 = (tid & 15) * 4;
      f32x4 a = {0.f, 0.f, 0.f, 0.f};
      float ls = 0.f;
#pragma unroll
      for (int ww = 0; ww < 8; ++ww) {
        a += *(const f32x4*)&om[ww * 2176 + row * 68 + c4];
        ls += om[ww * 2176 + row * 68 + 64];
      }
      float rl = 1.f / ls;
      *(f32x4*)&out[((size_t)b * NT + t_ * 32 + row) * NH + c4] = a * rl;
    }
  }
}

extern "C" void kernel_launch(void* const* d_in, const int* in_sizes, int n_in,
                              void* d_out, int out_size, void* d_ws, size_t ws_size,
                              hipStream_t stream) {
  const float* x  = (const float*)d_in[0];
  const float* wk = (const float*)d_in[1];
  const float* wq = (const float*)d_in[2];
  const float* wv = (const float*)d_in[3];
  float* out = (float*)d_out;

  u16* qg  = (u16*)d_ws;                 // [B*T][64] bf16
  u16* kg  = qg + NB * NT * NH;          // [B*T][64] bf16
  u16* vtg = kg + NB * NT * NH;          // [B][64][T] bf16
  u16* wb  = vtg + NB * NT * NH;         // [3][64][1024] bf16

  wconv<<<768, 256, 0, stream>>>(wk, wq, wv, wb);
  qkv_proj<<<256, 512, 0, stream>>>(x, wb, qg, kg, vtg);
  flash<<<256, 512, 0, stream>>>(qg, kg, vtg, out);
}

// Round 24
// 43.042 us; speedup vs baseline: 1.0544x; 1.0544x over previous
//
#include <hip/hip_runtime.h>
#include <hip/hip_bf16.h>

typedef short bf16x8 __attribute__((ext_vector_type(8)));
typedef float f32x4 __attribute__((ext_vector_type(4)));
typedef float f32x16 __attribute__((ext_vector_type(16)));
typedef unsigned short u16;
typedef u16 u16x8 __attribute__((ext_vector_type(8)));
typedef unsigned int u32;
typedef u32 u32x4 __attribute__((ext_vector_type(4)));

constexpr int NB = 8, NT = 2048, NC = 1024, NH = 64;
constexpr float L2E = 1.4426950408889634f;
constexpr float MBIAS = -23.083120654223414f;   // -16*log2(e): fixed softmax max

__device__ __forceinline__ u16 f2bf(float f) {
  __hip_bfloat16 h = __float2bfloat16(f);
  return __builtin_bit_cast(u16, h);
}
__device__ __forceinline__ bf16x8 ldsv8(const u16* p) {
  return __builtin_bit_cast(bf16x8, *(const u16x8*)p);
}
__device__ __forceinline__ u32 pk2(float a, float b) {
  return (u32)f2bf(a) | ((u32)f2bf(b) << 16);
}
__device__ __forceinline__ void glds16(const void* g, void* l) {
  __builtin_amdgcn_global_load_lds((const __attribute__((address_space(1))) void*)g,
                                   (__attribute__((address_space(3))) void*)l, 16, 0, 0);
}

// ---------------- kernel 0: W fp32 [C][H] -> bf16 W^T [3][H][C]; Wq scaled 0.125
__global__ __launch_bounds__(256) void wconv(const float* __restrict__ wk,
                                             const float* __restrict__ wq,
                                             const float* __restrict__ wv,
                                             u16* __restrict__ wb) {
  int idx = blockIdx.x * 256 + threadIdx.x;   // 3*64*1024
  int m = idx >> 16, rem = idx & 65535;
  int n = rem >> 10, kk = rem & 1023;
  const float* s = (m == 0) ? wq : ((m == 1) ? wk : wv);
  float f = s[kk * NH + n];
  if (m == 0) f *= 0.125f;
  wb[idx] = f2bf(f);
}

// ---------------- kernel 1: fused QKV projection — 2-deep pipelined staging (r16).
__global__ __launch_bounds__(512, 4)
__attribute__((amdgpu_waves_per_eu(4, 4)))
void qkv_proj(const float* __restrict__ x,
              const u16* __restrict__ wb,
              u16* __restrict__ qg,
              u16* __restrict__ kg,
              u16* __restrict__ vtg) {
  __shared__ __align__(16) float xbuf[2][32 * 64];
  __shared__ __align__(16) u16 wlds[2][192 * 64];
  __shared__ __align__(16) u16 vt[64][40];
  __shared__ __align__(16) u16 qs[32][72];
  __shared__ __align__(16) u16 ks_[32][72];
  const int tid = threadIdx.x, w = tid >> 6, l = tid & 63;
  const int lr = l & 15, lg = l >> 4;
  const int wr = w & 1, wc = w >> 1;
  const int row0 = blockIdx.x * 32;

  f32x4 acc[3];
#pragma unroll
  for (int nt = 0; nt < 3; ++nt) acc[nt] = (f32x4){0.f, 0.f, 0.f, 0.f};

#define GSTAGE(buf, kb)                                                       \
  {                                                                           \
    int row = w * 4 + (l >> 4);                                               \
    int srci = ((l & 15) * 16) ^ ((row & 7) << 4);                            \
    glds16((const char*)x + (size_t)(row0 + row) * 4096 + (kb) * 256 + srci,  \
           (char*)&xbuf[buf][0] + w * 1024);                                  \
    _Pragma("unroll")                                                         \
    for (int i = 0; i < 3; ++i) {                                             \
      int seg = w * 3 + i;                                                    \
      int wrow = seg * 8 + (l >> 3);                                          \
      int wsrc = ((l & 7) * 16) ^ ((wrow & 7) << 4);                          \
      glds16((const char*)wb + (size_t)wrow * 2048 + (kb) * 128 + wsrc,       \
             (char*)&wlds[buf][0] + seg * 1024);                              \
    }                                                                         \
  }

  GSTAGE(0, 0);
  GSTAGE(1, 1);

#pragma unroll
  for (int kb = 0; kb < 16; ++kb) {
    const int cur = kb & 1;
    if (kb < 15) {
      asm volatile("s_waitcnt vmcnt(4)" ::: "memory");
    } else {
      asm volatile("s_waitcnt vmcnt(0)" ::: "memory");
    }
    __builtin_amdgcn_sched_barrier(0);
    __builtin_amdgcn_s_barrier();
    f32x4 xv[2][2];
#pragma unroll
    for (int ks = 0; ks < 2; ++ks) {
      int rowl = wr * 16 + lr;
      int sz = (lr & 7) << 4;
      int c0 = ks * 128 + lg * 32;
      xv[ks][0] = *(const f32x4*)((const char*)&xbuf[cur][0] + rowl * 256 + (c0 ^ sz));
      xv[ks][1] = *(const f32x4*)((const char*)&xbuf[cur][0] + rowl * 256 + ((c0 + 16) ^ sz));
    }
    bf16x8 bfr[3][2];
#pragma unroll
    for (int nt = 0; nt < 3; ++nt)
#pragma unroll
      for (int ks = 0; ks < 2; ++ks) {
        int wrow = wc * 48 + nt * 16 + lr;
        int cb = (ks * 64 + lg * 16) ^ ((lr & 7) << 4);
        bfr[nt][ks] = ldsv8((const u16*)((const char*)&wlds[cur][0] + wrow * 128 + cb));
      }
    asm volatile("s_waitcnt lgkmcnt(0)" ::: "memory");
    __builtin_amdgcn_sched_barrier(0);
    __builtin_amdgcn_s_barrier();
    if (kb < 14) GSTAGE(cur, kb + 2);
    bf16x8 af[2];
#pragma unroll
    for (int ks = 0; ks < 2; ++ks) {
      u16x8 tt;
#pragma unroll
      for (int j = 0; j < 4; ++j) {
        tt[j]     = f2bf(xv[ks][0][j]);
        tt[j + 4] = f2bf(xv[ks][1][j]);
      }
      af[ks] = __builtin_bit_cast(bf16x8, tt);
    }
#pragma unroll
    for (int nt = 0; nt < 3; ++nt)
#pragma unroll
      for (int ks = 0; ks < 2; ++ks)
        acc[nt] = __builtin_amdgcn_mfma_f32_16x16x32_bf16(af[ks], bfr[nt][ks], acc[nt], 0, 0, 0);
  }
#undef GSTAGE

#pragma unroll
  for (int nt = 0; nt < 3; ++nt)
#pragma unroll
    for (int r = 0; r < 4; ++r) {
      int g = wc * 48 + nt * 16 + lr;
      int rl = wr * 16 + lg * 4 + r;
      u16 bv = f2bf(acc[nt][r]);
      if (g < 64)       qs[rl][g] = bv;
      else if (g < 128) ks_[rl][g - 64] = bv;
      else              vt[g - 128][rl] = bv;
    }
  __syncthreads();
  if (tid < 256) {
    int b = row0 >> 11, t0 = row0 & 2047;
    {
      int row = tid >> 3, c8 = (tid & 7) * 8;
      *(u16x8*)(qg + (size_t)(row0 + row) * NH + c8) = *(const u16x8*)&qs[row][c8];
      *(u16x8*)(kg + (size_t)(row0 + row) * NH + c8) = *(const u16x8*)&ks_[row][c8];
    }
    {
      int h = tid >> 2, tc = (tid & 3) * 8;
      u16x8 vv = *(const u16x8*)&vt[h][tc];
      *(u16x8*)(vtg + ((size_t)b * NH + h) * NT + t0 + tc) = vv;
    }
  }
}

// ---------------- kernel 2: causal flash — merged-pair blocks for full TLP (r20).
__global__ __launch_bounds__(512, 2)
__attribute__((amdgpu_waves_per_eu(2, 2)))
void flash(const u16* __restrict__ qg,
           const u16* __restrict__ kg,
           const u16* __restrict__ vtg,
           float* __restrict__ out) {
  __shared__ __align__(16) u16 stg[8][2][4096];     // 128 KB: [wave][K/V][64x64]
  float* om = (float*)&stg[0][0][0];                // [8][32][68] f32 aliased
  const int tid = threadIdx.x, w = tid >> 6, l = tid & 63;
  const int l31 = l & 31, hb = l >> 5;
  const int b = blockIdx.x & 7, gp = blockIdx.x >> 3;   // gp = 0..31
  const int tA = gp, tB = 63 - gp;
  const int nktA = (tA + 2) >> 1, nktB = (tB + 2) >> 1;
  const int ntot = nktA + nktB;

  bf16x8 qfA[4], qfB[4];
  {
    const u16* qpA = qg + ((size_t)b * NT + tA * 32 + l31) * NH;
    const u16* qpB = qg + ((size_t)b * NT + tB * 32 + l31) * NH;
#pragma unroll
    for (int ks = 0; ks < 4; ++ks) {
      qfA[ks] = ldsv8(qpA + ks * 16 + hb * 8);
      qfB[ks] = ldsv8(qpB + ks * 16 + hb * 8);
    }
  }
  f32x16 oA0, oA1, oB0, oB1;
#pragma unroll
  for (int r = 0; r < 16; ++r) { oA0[r] = 0.f; oA1[r] = 0.f; oB0[r] = 0.f; oB1[r] = 0.f; }
  float lsA = 0.f, lsB = 0.f;
  const char* kbase = (const char*)(kg + (size_t)b * NT * NH);
  const char* vbase = (const char*)(vtg + (size_t)b * NH * NT);
  char* kst = (char*)&stg[w][0][0];
  char* vst = (char*)&stg[w][1][0];

#define STAGE_K(kt_)                                                          \
  {                                                                           \
    const int kvb_ = (kt_) * 64;                                              \
    int r8 = l >> 3;                                                          \
    int src = ((l & 7) * 16) ^ (r8 << 4);                                     \
    _Pragma("unroll")                                                         \
    for (int j = 0; j < 8; ++j)                                               \
      glds16(kbase + (size_t)(kvb_ + j * 8 + r8) * 128 + src, kst + j * 1024);\
  }
#define STAGE_V(kt_)                                                          \
  {                                                                           \
    const int kvb_ = (kt_) * 64;                                              \
    int r8 = l >> 3;                                                          \
    int src = ((l & 7) * 16) ^ (r8 << 4);                                     \
    _Pragma("unroll")                                                         \
    for (int j = 0; j < 8; ++j)                                               \
      glds16(vbase + (size_t)(j * 8 + r8) * 4096 + kvb_ * 2 + src, vst + j * 1024);\
  }
#define KT_OF(c_) (((c_) < nktA) ? (c_) : ((c_) - nktA))

  { const int kt0 = KT_OF(w); STAGE_K(kt0); STAGE_V(kt0); }

#pragma unroll 1
  for (int c = w; c < ntot; c += 8) {
    const bool isA = (c < nktA);
    const int kt = isA ? c : (c - nktA);
    const int t_ = isA ? tA : tB;
    const int kvb = kt * 64;
    const bool pre = (c + 8 < ntot);
    const int ktn = pre ? KT_OF(c + 8) : 0;
    asm volatile("s_waitcnt vmcnt(8)" ::: "memory");
    __builtin_amdgcn_sched_barrier(0);
    const int key = (l31 & 7) << 4;
    bf16x8 kf[4][2];
#pragma unroll
    for (int ks = 0; ks < 4; ++ks)
#pragma unroll
      for (int half = 0; half < 2; ++half) {
        int row = half * 32 + l31;
        int col = ks * 32 + hb * 16;
        kf[ks][half] = ldsv8((const u16*)(kst + row * 128 + (col ^ key)));
      }
    asm volatile("s_waitcnt lgkmcnt(0)" ::: "memory");
    __builtin_amdgcn_sched_barrier(0);
    if (pre) STAGE_K(ktn);

    f32x16 s0, s1;
#pragma unroll
    for (int r = 0; r < 16; ++r) { s0[r] = 0.f; s1[r] = 0.f; }
    __builtin_amdgcn_s_setprio(1);
    if (isA) {
#pragma unroll
      for (int ks = 0; ks < 4; ++ks) {
        s0 = __builtin_amdgcn_mfma_f32_32x32x16_bf16(kf[ks][0], qfA[ks], s0, 0, 0, 0);
        s1 = __builtin_amdgcn_mfma_f32_32x32x16_bf16(kf[ks][1], qfA[ks], s1, 0, 0, 0);
      }
    } else {
#pragma unroll
      for (int ks = 0; ks < 4; ++ks) {
        s0 = __builtin_amdgcn_mfma_f32_32x32x16_bf16(kf[ks][0], qfB[ks], s0, 0, 0, 0);
        s1 = __builtin_amdgcn_mfma_f32_32x32x16_bf16(kf[ks][1], qfB[ks], s1, 0, 0, 0);
      }
    }
    __builtin_amdgcn_s_setprio(0);
    if (kvb + 63 > t_ * 32) {
      const int qrow_ = t_ * 32 + l31;
#pragma unroll
      for (int r = 0; r < 16; ++r) {
        int kv0 = kvb + (r & 3) + 8 * (r >> 2) + 4 * hb;
        if (kv0 > qrow_)      s0[r] = -1e30f;
        if (kv0 + 32 > qrow_) s1[r] = -1e30f;
      }
    }
    float p0[16], p1[16];
    float lst = 0.f;
#pragma unroll
    for (int r = 0; r < 16; ++r) {
      p0[r] = exp2f(fmaf(s0[r], L2E, MBIAS));
      p1[r] = exp2f(fmaf(s1[r], L2E, MBIAS));
      lst += p0[r] + p1[r];
    }
    if (isA) lsA += lst; else lsB += lst;
    u32 pf[2][2][4];
#pragma unroll
    for (int kvt = 0; kvt < 2; ++kvt) {
      const float* pp = kvt ? p1 : p0;
#pragma unroll
      for (int ks2 = 0; ks2 < 2; ++ks2) {
        u32 a0 = pk2(pp[8 * ks2 + 0], pp[8 * ks2 + 1]);
        u32 a1 = pk2(pp[8 * ks2 + 2], pp[8 * ks2 + 3]);
        u32 b0 = pk2(pp[8 * ks2 + 4], pp[8 * ks2 + 5]);
        u32 b1 = pk2(pp[8 * ks2 + 6], pp[8 * ks2 + 7]);
        u32 e0 = hb ? a0 : b0, e1 = hb ? a1 : b1;
        e0 = __shfl_xor(e0, 32);
        e1 = __shfl_xor(e1, 32);
        pf[kvt][ks2][0] = hb ? e0 : a0;
        pf[kvt][ks2][1] = hb ? e1 : a1;
        pf[kvt][ks2][2] = hb ? b0 : e0;
        pf[kvt][ks2][3] = hb ? b1 : e1;
      }
    }
    if (pre) {
      asm volatile("s_waitcnt vmcnt(8)" ::: "memory");
    } else {
      asm volatile("s_waitcnt vmcnt(0)" ::: "memory");
    }
    __builtin_amdgcn_sched_barrier(0);
    bf16x8 vf[2][2][2];
#pragma unroll
    for (int ht = 0; ht < 2; ++ht)
#pragma unroll
      for (int kvt = 0; kvt < 2; ++kvt)
#pragma unroll
        for (int ks2 = 0; ks2 < 2; ++ks2) {
          int row = ht * 32 + l31;
          int col = kvt * 64 + ks2 * 32 + hb * 16;
          vf[ht][kvt][ks2] = ldsv8((const u16*)(vst + row * 128 + (col ^ key)));
        }
    asm volatile("s_waitcnt lgkmcnt(0)" ::: "memory");
    __builtin_amdgcn_sched_barrier(0);
    if (pre) STAGE_V(ktn);

    __builtin_amdgcn_s_setprio(1);
    if (isA) {
#pragma unroll
      for (int ht = 0; ht < 2; ++ht)
#pragma unroll
        for (int kvt = 0; kvt < 2; ++kvt)
#pragma unroll
          for (int ks2 = 0; ks2 < 2; ++ks2) {
            u32x4 pw = {pf[kvt][ks2][0], pf[kvt][ks2][1], pf[kvt][ks2][2], pf[kvt][ks2][3]};
            bf16x8 pv = __builtin_bit_cast(bf16x8, pw);
            if (ht == 0) oA0 = __builtin_amdgcn_mfma_f32_32x32x16_bf16(vf[0][kvt][ks2], pv, oA0, 0, 0, 0);
            else         oA1 = __builtin_amdgcn_mfma_f32_32x32x16_bf16(vf[1][kvt][ks2], pv, oA1, 0, 0, 0);
          }
    } else {
#pragma unroll
      for (int ht = 0; ht < 2; ++ht)
#pragma unroll
        for (int kvt = 0; kvt < 2; ++kvt)
#pragma unroll
          for (int ks2 = 0; ks2 < 2; ++ks2) {
            u32x4 pw = {pf[kvt][ks2][0], pf[kvt][ks2][1], pf[kvt][ks2][2], pf[kvt][ks2][3]};
            bf16x8 pv = __builtin_bit_cast(bf16x8, pw);
            if (ht == 0) oB0 = __builtin_amdgcn_mfma_f32_32x32x16_bf16(vf[0][kvt][ks2], pv, oB0, 0, 0, 0);
            else         oB1 = __builtin_amdgcn_mfma_f32_32x32x16_bf16(vf[1][kvt][ks2], pv, oB1, 0, 0, 0);
          }
    }
    __builtin_amdgcn_s_setprio(0);
  }
#undef STAGE_K
#undef STAGE_V
#undef KT_OF
  lsA += __shfl_xor(lsA, 32);
  lsB += __shfl_xor(lsB, 32);

#pragma unroll 1
  for (int ph = 0; ph < 2; ++ph) {
    __syncthreads();
    {
      float* dst = &om[w * 2176 + l31 * 68];
#pragma unroll
      for (int ht = 0; ht < 2; ++ht)
#pragma unroll
        for (int rq = 0; rq < 4; ++rq) {
          f32x4 q4;
#pragma unroll
          for (int cc = 0; cc < 4; ++cc) {
            int idx = 4 * rq + cc;
            q4[cc] = ph ? (ht ? oB1[idx] : oB0[idx]) : (ht ? oA1[idx] : oA0[idx]);
          }
          *(f32x4*)&dst[ht * 32 + rq * 8 + hb * 4] = q4;
        }
      if (hb == 0) dst[64] = ph ? lsB : lsA;
    }
    __syncthreads();
    {
      const int t_ = ph ? tB : tA;
      int row = tid >> 4, c4 = (tid & 15) * 4;
      f32x4 a = {0.f, 0.f, 0.f, 0.f};
      float ls = 0.f;
#pragma unroll
      for (int ww = 0; ww < 8; ++ww) {
        a += *(const f32x4*)&om[ww * 2176 + row * 68 + c4];
        ls += om[ww * 2176 + row * 68 + 64];
      }
      float rl = 1.f / ls;
      *(f32x4*)&out[((size_t)b * NT + t_ * 32 + row) * NH + c4] = a * rl;
    }
  }
}

extern "C" void kernel_launch(void* const* d_in, const int* in_sizes, int n_in,
                              void* d_out, int out_size, void* d_ws, size_t ws_size,
                              hipStream_t stream) {
  const float* x  = (const float*)d_in[0];
  const float* wk = (const float*)d_in[1];
  const float* wq = (const float*)d_in[2];
  const float* wv = (const float*)d_in[3];
  float* out = (float*)d_out;

  u16* qg  = (u16*)d_ws;                 // [B*T][64] bf16
  u16* kg  = qg + NB * NT * NH;          // [B*T][64] bf16
  u16* vtg = kg + NB * NT * NH;          // [B][64][T] bf16
  u16* wb  = vtg + NB * NT * NH;         // [3][64][1024] bf16

  wconv<<<768, 256, 0, stream>>>(wk, wq, wv, wb);
  qkv_proj<<<512, 512, 0, stream>>>(x, wb, qg, kg, vtg);
  flash<<<256, 512, 0, stream>>>(qg, kg, vtg, out);
}